// Round 9
// baseline (1027.109 us; speedup 1.0000x reference)
//
#include <hip/hip_runtime.h>

// NodeModel: agg = segment_sum(x[row], col); h = concat(x, agg); out = MLP(h).
//
// Path A:
//   0) pad x -> x4 (float4/node): gather = one aligned 16B load.
//   1) counting-sort edges by col-bucket (col>>12, 245 cursors, proven
//      write-combining-safe); payload (row<<12)|col_local (exact u32, N<2^20).
//   2) reorder: per col-bucket block, 256-bin counting sort by p>>24
//      (= row>>12, 4096-node / 64KB x4 windows) -> packed2.
//   3) agg: per col-bucket, stream packed2 (row-monotone within bucket ->
//      gathers walk x4 windows; all blocks in phase -> windows L2-resident),
//      LDS-atomic accumulate, fused node MLP epilogue.
// Path B (smaller ws): same but no x4/reorder -> round-3 gather agg (728us).
// Path C: global atomicAdd + separate MLP.

#define SH    12
#define TILE  4096            // nodes per col-bucket (48 KB LDS acc)
#define MAXNB 256
#define NBLK  512             // edge chunks for hist/scatter
#define THR   1024

// ---------------- sort kernels ----------------

__global__ __launch_bounds__(THR) void hist_kernel(
    const int* __restrict__ key, int* __restrict__ hist,
    int nb, int chunk, int n_edges)
{
    __shared__ int lh[MAXNB];
    const int t = threadIdx.x, b = blockIdx.x;
    for (int k = t; k < nb; k += THR) lh[k] = 0;
    __syncthreads();

    long long s = (long long)b * chunk;
    long long e = s + chunk; if (e > n_edges) e = n_edges;
    if (s < e) {
        const int n = (int)(e - s);
        const int n4 = n >> 2;
        const int4* __restrict__ k4p = reinterpret_cast<const int4*>(key + s);
        for (int i = t; i < n4; i += THR) {
            int4 c = k4p[i];
            atomicAdd(&lh[(unsigned)c.x >> SH], 1);
            atomicAdd(&lh[(unsigned)c.y >> SH], 1);
            atomicAdd(&lh[(unsigned)c.z >> SH], 1);
            atomicAdd(&lh[(unsigned)c.w >> SH], 1);
        }
        for (int i = (n4 << 2) + t; i < n; i += THR)
            atomicAdd(&lh[(unsigned)key[s + i] >> SH], 1);
    }
    __syncthreads();
    for (int k = t; k < nb; k += THR) hist[(size_t)b * nb + k] = lh[k];
}

__global__ __launch_bounds__(NBLK) void scan_blocks_kernel(
    int* __restrict__ hist, int* __restrict__ keyTotal, int nb)
{
    __shared__ int sd[NBLK];
    const int t = threadIdx.x, k = blockIdx.x;
    const int v = hist[(size_t)t * nb + k];
    sd[t] = v; __syncthreads();
#pragma unroll
    for (int off = 1; off < NBLK; off <<= 1) {
        int a = (t >= off) ? sd[t - off] : 0;
        __syncthreads();
        sd[t] += a;
        __syncthreads();
    }
    hist[(size_t)t * nb + k] = sd[t] - v;
    if (t == NBLK - 1) keyTotal[k] = sd[t];
}

__global__ __launch_bounds__(1024) void scan_keys_kernel(
    const int* __restrict__ keyTotal, int* __restrict__ keyStart, int nb)
{
    __shared__ int sd[1024];
    const int t = threadIdx.x;
    const int v = (t < nb) ? keyTotal[t] : 0;
    sd[t] = v; __syncthreads();
#pragma unroll
    for (int off = 1; off < 1024; off <<= 1) {
        int a = (t >= off) ? sd[t - off] : 0;
        __syncthreads();
        sd[t] += a;
        __syncthreads();
    }
    if (t < nb) keyStart[t] = sd[t] - v;
    if (t == 0) keyStart[nb] = sd[1023];
}

__global__ __launch_bounds__(THR) void scatter_kernel(
    const int* __restrict__ key, const int* __restrict__ other,
    const int* __restrict__ hist, const int* __restrict__ keyStart,
    unsigned* __restrict__ packed, int nb, int chunk, int n_edges)
{
    __shared__ int lc[MAXNB];
    const int t = threadIdx.x, b = blockIdx.x;
    for (int k = t; k < nb; k += THR)
        lc[k] = keyStart[k] + hist[(size_t)b * nb + k];
    __syncthreads();

    long long s = (long long)b * chunk;
    long long e = s + chunk; if (e > n_edges) e = n_edges;
    if (s < e) {
        const int n = (int)(e - s);
        const int n4 = n >> 2;
        const int4* __restrict__ k4p = reinterpret_cast<const int4*>(key + s);
        const int4* __restrict__ o4p = reinterpret_cast<const int4*>(other + s);
        for (int i = t; i < n4; i += THR) {
            int4 c = k4p[i];
            int4 r = o4p[i];
            int p;
            p = atomicAdd(&lc[(unsigned)c.x >> SH], 1);
            packed[p] = ((unsigned)r.x << SH) | ((unsigned)c.x & (TILE - 1));
            p = atomicAdd(&lc[(unsigned)c.y >> SH], 1);
            packed[p] = ((unsigned)r.y << SH) | ((unsigned)c.y & (TILE - 1));
            p = atomicAdd(&lc[(unsigned)c.z >> SH], 1);
            packed[p] = ((unsigned)r.z << SH) | ((unsigned)c.z & (TILE - 1));
            p = atomicAdd(&lc[(unsigned)c.w >> SH], 1);
            packed[p] = ((unsigned)r.w << SH) | ((unsigned)c.w & (TILE - 1));
        }
        for (int i = (n4 << 2) + t; i < n; i += THR) {
            int c = key[s + i], r = other[s + i];
            int p = atomicAdd(&lc[(unsigned)c >> SH], 1);
            packed[p] = ((unsigned)r << SH) | ((unsigned)c & (TILE - 1));
        }
    }
}

// ---------------- x padding ----------------

__global__ __launch_bounds__(256) void pad_x_kernel(
    const float* __restrict__ x, float4* __restrict__ x4, int n)
{
    const int stride = gridDim.x * 256;
    for (int i = blockIdx.x * 256 + threadIdx.x; i < n; i += stride) {
        float4 v;
        v.x = x[3 * i + 0];
        v.y = x[3 * i + 1];
        v.z = x[3 * i + 2];
        v.w = 0.0f;
        x4[i] = v;
    }
}

// ---------------- per-bucket row reorder (256-bin counting sort) --------

__global__ __launch_bounds__(THR) void reorder_kernel(
    const unsigned* __restrict__ packed, unsigned* __restrict__ packed2,
    const int* __restrict__ keyStart)
{
    __shared__ int h[256];
    __shared__ int sd[256];
    __shared__ int cur[256];
    const int t = threadIdx.x, cb = blockIdx.x;
    if (t < 256) h[t] = 0;
    __syncthreads();

    const int s = keyStart[cb], e = keyStart[cb + 1];

    // pass 1: 256-bin histogram of row>>12 (= p>>24)
    for (int i = s + t; i < e; i += THR)
        atomicAdd(&h[packed[i] >> 24], 1);
    __syncthreads();

    // inclusive scan of h in LDS (all threads hit the barriers)
    if (t < 256) sd[t] = h[t];
    __syncthreads();
#pragma unroll
    for (int off = 1; off < 256; off <<= 1) {
        int a = 0;
        if (t < 256 && t >= off) a = sd[t - off];
        __syncthreads();
        if (t < 256) sd[t] += a;
        __syncthreads();
    }
    if (t < 256) cur[t] = s + sd[t] - h[t];   // exclusive + segment base
    __syncthreads();

    // pass 2: scatter into row-sorted order (runs ~1.6KB, within-block)
    for (int i = s + t; i < e; i += THR) {
        unsigned p = packed[i];
        int q = atomicAdd(&cur[p >> 24], 1);
        packed2[q] = p;
    }
}

// ---------------- agg + fused MLP ----------------

template <bool USE_X4>
__global__ __launch_bounds__(THR) void agg_mlp_kernel(
    const unsigned* __restrict__ pk, const float4* __restrict__ x4,
    const float* __restrict__ x, const int* __restrict__ keyStart,
    const float* __restrict__ W1, const float* __restrict__ b1,
    const float* __restrict__ W2, const float* __restrict__ b2,
    const float* __restrict__ W3, const float* __restrict__ b3,
    float* __restrict__ out, int n_nodes)
{
    __shared__ float acc[TILE * 3];   // 48 KB
    __shared__ float sW1[96], sb1[16], sW2[256], sb2[16], sW3[48], sb3[3];
    const int t = threadIdx.x, cb = blockIdx.x;

    if (t < 96)  sW1[t] = W1[t];
    if (t < 16)  sb1[t] = b1[t];
    if (t < 256) sW2[t] = W2[t];
    if (t >= 256 && t < 272) sb2[t - 256] = b2[t - 256];
    if (t >= 272 && t < 320) sW3[t - 272] = W3[t - 272];
    if (t >= 320 && t < 323) sb3[t - 320] = b3[t - 320];
    for (int f = t; f < TILE * 3; f += THR) acc[f] = 0.0f;
    __syncthreads();

    const int s = keyStart[cb], e = keyStart[cb + 1];

    auto add1 = [&](unsigned p) {
        const int j = (int)(p & (TILE - 1)) * 3;
        if (USE_X4) {
            float4 v = x4[p >> SH];
            atomicAdd(&acc[j + 0], v.x);
            atomicAdd(&acc[j + 1], v.y);
            atomicAdd(&acc[j + 2], v.z);
        } else {
            const float* __restrict__ xs = x + 3ll * (p >> SH);
            atomicAdd(&acc[j + 0], xs[0]);
            atomicAdd(&acc[j + 1], xs[1]);
            atomicAdd(&acc[j + 2], xs[2]);
        }
    };

    int i = s + t;
    for (; i + 3 * THR < e; i += 4 * THR) {
        unsigned p0 = pk[i];
        unsigned p1 = pk[i + THR];
        unsigned p2 = pk[i + 2 * THR];
        unsigned p3 = pk[i + 3 * THR];
        add1(p0); add1(p1); add1(p2); add1(p3);
    }
    for (; i < e; i += THR) add1(pk[i]);
    __syncthreads();

    const long long base = (long long)cb << SH;
    long long lim = (long long)n_nodes - base;
    if (lim > TILE) lim = TILE;
    if (lim <= 0) return;

    for (int j = t; j < (int)lim; j += THR) {
        const long long node = base + j;
        float in6[6];
        in6[0] = x[3 * node + 0];
        in6[1] = x[3 * node + 1];
        in6[2] = x[3 * node + 2];
        in6[3] = acc[3 * j + 0];
        in6[4] = acc[3 * j + 1];
        in6[5] = acc[3 * j + 2];

        float h1[16];
#pragma unroll
        for (int q = 0; q < 16; ++q) {
            float sv = sb1[q];
#pragma unroll
            for (int r = 0; r < 6; ++r) sv = fmaf(in6[r], sW1[r * 16 + q], sv);
            h1[q] = fmaxf(sv, 0.0f);
        }
        float h2[16];
#pragma unroll
        for (int q = 0; q < 16; ++q) {
            float sv = sb2[q];
#pragma unroll
            for (int r = 0; r < 16; ++r) sv = fmaf(h1[r], sW2[r * 16 + q], sv);
            h2[q] = fmaxf(sv, 0.0f);
        }
        float o0 = sb3[0], o1 = sb3[1], o2 = sb3[2];
#pragma unroll
        for (int q = 0; q < 16; ++q) {
            o0 = fmaf(h2[q], sW3[q * 3 + 0], o0);
            o1 = fmaf(h2[q], sW3[q * 3 + 1], o1);
            o2 = fmaf(h2[q], sW3[q * 3 + 2], o2);
        }
        out[3 * node + 0] = o0;
        out[3 * node + 1] = o1;
        out[3 * node + 2] = o2;
    }
}

// ---------------- Path C ----------------

__global__ __launch_bounds__(256) void edge_scatter_kernel(
    const int* __restrict__ rows, const int* __restrict__ cols,
    const float* __restrict__ x, float* __restrict__ agg, int n_edges)
{
    const long long tid = (long long)blockIdx.x * blockDim.x + threadIdx.x;
    const long long stride = (long long)gridDim.x * blockDim.x;
    for (long long i = tid; i < n_edges; i += stride) {
        int r = rows[i], c = cols[i];
        const float* xs = x + 3ll * r; float* a = agg + 3ll * c;
        atomicAdd(a + 0, xs[0]); atomicAdd(a + 1, xs[1]); atomicAdd(a + 2, xs[2]);
    }
}

__global__ __launch_bounds__(256) void node_mlp_kernel(
    const float* __restrict__ x,
    const float* __restrict__ W1, const float* __restrict__ b1,
    const float* __restrict__ W2, const float* __restrict__ b2,
    const float* __restrict__ W3, const float* __restrict__ b3,
    float* __restrict__ out, int n_nodes)
{
    __shared__ float sW1[96], sb1[16], sW2[256], sb2[16], sW3[48], sb3[3];
    const int t = threadIdx.x;
    if (t < 96)  sW1[t] = W1[t];
    if (t < 16)  sb1[t] = b1[t];
    sW2[t] = W2[t];
    if (t < 16)  sb2[t] = b2[t];
    if (t < 48)  sW3[t] = W3[t];
    if (t < 3)   sb3[t] = b3[t];
    __syncthreads();

    const int i = blockIdx.x * 256 + t;
    if (i >= n_nodes) return;

    float in6[6];
    in6[0] = x[3 * i + 0];
    in6[1] = x[3 * i + 1];
    in6[2] = x[3 * i + 2];
    in6[3] = out[3 * i + 0];
    in6[4] = out[3 * i + 1];
    in6[5] = out[3 * i + 2];

    float h1[16];
#pragma unroll
    for (int j = 0; j < 16; ++j) {
        float s = sb1[j];
#pragma unroll
        for (int k = 0; k < 6; ++k) s = fmaf(in6[k], sW1[k * 16 + j], s);
        h1[j] = fmaxf(s, 0.0f);
    }
    float h2[16];
#pragma unroll
    for (int j = 0; j < 16; ++j) {
        float s = sb2[j];
#pragma unroll
        for (int k = 0; k < 16; ++k) s = fmaf(h1[k], sW2[k * 16 + j], s);
        h2[j] = fmaxf(s, 0.0f);
    }
    float o[3];
#pragma unroll
    for (int c = 0; c < 3; ++c) {
        float s = sb3[c];
#pragma unroll
        for (int j = 0; j < 16; ++j) s = fmaf(h2[j], sW3[j * 3 + c], s);
        o[c] = s;
    }
    out[3 * i + 0] = o[0];
    out[3 * i + 1] = o[1];
    out[3 * i + 2] = o[2];
}

extern "C" void kernel_launch(void* const* d_in, const int* in_sizes, int n_in,
                              void* d_out, int out_size, void* d_ws, size_t ws_size,
                              hipStream_t stream) {
    const float* x   = (const float*)d_in[0];
    const int*   ei  = (const int*)d_in[1];   // [2, E] int32
    const float* W1  = (const float*)d_in[5];
    const float* b1  = (const float*)d_in[6];
    const float* W2  = (const float*)d_in[7];
    const float* b2  = (const float*)d_in[8];
    const float* W3  = (const float*)d_in[9];
    const float* b3  = (const float*)d_in[10];

    const int n_nodes = in_sizes[0] / 3;
    const int n_edges = in_sizes[1] / 2;
    const int* rows = ei;            // edge_index[0]
    const int* cols = ei + n_edges;  // edge_index[1]
    float* out = (float*)d_out;

    const int nb = (n_nodes + TILE - 1) >> SH;

    int chunk = (n_edges + NBLK - 1) / NBLK;
    chunk = (chunk + 3) & ~3;        // keep per-block int4 loads 16B-aligned

    // Path A layout: x4[N] f4 | packed[E] | packed2[E] | hist[NBLK*nb]
    //                | keyTotal[nb] | keyStart[nb+1]
    const size_t off_x4     = 0;
    const size_t off_packed = off_x4 + (size_t)n_nodes * 16;
    const size_t off_pk2    = off_packed + (size_t)n_edges * 4;
    const size_t off_hist   = off_pk2 + (size_t)n_edges * 4;
    const size_t off_kt     = off_hist + (size_t)NBLK * nb * 4;
    const size_t off_ks     = off_kt + (size_t)nb * 4;
    const size_t needA      = off_ks + (size_t)(nb + 1) * 4;

    const size_t needB = (size_t)n_edges * 4 + (size_t)NBLK * nb * 4
                       + (size_t)nb * 4 + (size_t)(nb + 1) * 4;
    const bool okA = (ws_size >= needA) && (nb <= MAXNB) && (n_nodes <= (1 << 20));
    const bool okB = (ws_size >= needB) && (nb <= MAXNB) && (n_nodes <= (1 << 20));

    if (okA) {
        float4*   x4       = (float4*)((char*)d_ws + off_x4);
        unsigned* packed   = (unsigned*)((char*)d_ws + off_packed);
        unsigned* packed2  = (unsigned*)((char*)d_ws + off_pk2);
        int*      hist     = (int*)((char*)d_ws + off_hist);
        int*      keyTotal = (int*)((char*)d_ws + off_kt);
        int*      keyStart = (int*)((char*)d_ws + off_ks);

        pad_x_kernel<<<2048, 256, 0, stream>>>(x, x4, n_nodes);
        hist_kernel<<<NBLK, THR, 0, stream>>>(cols, hist, nb, chunk, n_edges);
        scan_blocks_kernel<<<nb, NBLK, 0, stream>>>(hist, keyTotal, nb);
        scan_keys_kernel<<<1, 1024, 0, stream>>>(keyTotal, keyStart, nb);
        scatter_kernel<<<NBLK, THR, 0, stream>>>(cols, rows, hist, keyStart,
                                                 packed, nb, chunk, n_edges);
        reorder_kernel<<<nb, THR, 0, stream>>>(packed, packed2, keyStart);
        agg_mlp_kernel<true><<<nb, THR, 0, stream>>>(packed2, x4, x, keyStart,
                                                     W1, b1, W2, b2, W3, b3,
                                                     out, n_nodes);
    } else if (okB) {
        unsigned* packed = (unsigned*)d_ws;
        int* hist        = (int*)(packed + n_edges);
        int* keyTotal    = hist + (size_t)NBLK * nb;
        int* keyStart    = keyTotal + nb;

        hist_kernel<<<NBLK, THR, 0, stream>>>(cols, hist, nb, chunk, n_edges);
        scan_blocks_kernel<<<nb, NBLK, 0, stream>>>(hist, keyTotal, nb);
        scan_keys_kernel<<<1, 1024, 0, stream>>>(keyTotal, keyStart, nb);
        scatter_kernel<<<NBLK, THR, 0, stream>>>(cols, rows, hist, keyStart,
                                                 packed, nb, chunk, n_edges);
        agg_mlp_kernel<false><<<nb, THR, 0, stream>>>(packed, nullptr, x, keyStart,
                                                      W1, b1, W2, b2, W3, b3,
                                                      out, n_nodes);
    } else {
        hipMemsetAsync(d_out, 0, (size_t)out_size * sizeof(float), stream);
        edge_scatter_kernel<<<8192, 256, 0, stream>>>(rows, cols, x, out, n_edges);
        node_mlp_kernel<<<(n_nodes + 255) / 256, 256, 0, stream>>>(
            x, W1, b1, W2, b2, W3, b3, out, n_nodes);
    }
}

// Round 10
// 823.383 us; speedup vs baseline: 1.2474x; 1.2474x over previous
//
#include <hip/hip_runtime.h>

// NodeModel: agg = segment_sum(x[row], col); h = concat(x, agg); out = MLP(h).
//
// Path A:
//   0) pad x -> x4 (float4/node): gather = one aligned 16B load.
//   1) counting-sort by col-bucket (col>>12, 245 cursors = proven
//      write-combining-safe); payload (row<<12)|col_local (exact u32, N<2^20).
//   2) reorder: per col-bucket, 256-bin counting sort by row>>12 -> packed2
//      (row-monotone per bucket -> adjacent gathers share 64B lines);
//      also emits 8 row-window (row>>17, 2MB x4) sub-segment offsets.
//   3) agg_win: grid = 8 windows x 245 buckets (w-major). Block (w,cb)
//      gathers only from window w's 2MB x4 slice -> in-order dispatch keeps
//      active windows L2-resident per XCD. LDS acc -> partial[w] tile.
//   4) merge 8 partials + fused node MLP -> out.
// Path B (smaller ws): col-sort + direct gather agg (round-3, 728us).
// Path C: global atomicAdd + separate MLP.

#define SH    12
#define TILE  4096            // nodes per col-bucket (48 KB LDS acc)
#define MAXNB 256
#define NBLK  512             // edge chunks for hist/scatter
#define THR   1024
#define NWIN  8               // row windows (row>>17); 2MB of x4 each

// ---------------- sort kernels ----------------

__global__ __launch_bounds__(THR) void hist_kernel(
    const int* __restrict__ key, int* __restrict__ hist,
    int nb, int chunk, int n_edges)
{
    __shared__ int lh[MAXNB];
    const int t = threadIdx.x, b = blockIdx.x;
    for (int k = t; k < nb; k += THR) lh[k] = 0;
    __syncthreads();

    long long s = (long long)b * chunk;
    long long e = s + chunk; if (e > n_edges) e = n_edges;
    if (s < e) {
        const int n = (int)(e - s);
        const int n4 = n >> 2;
        const int4* __restrict__ k4p = reinterpret_cast<const int4*>(key + s);
        for (int i = t; i < n4; i += THR) {
            int4 c = k4p[i];
            atomicAdd(&lh[(unsigned)c.x >> SH], 1);
            atomicAdd(&lh[(unsigned)c.y >> SH], 1);
            atomicAdd(&lh[(unsigned)c.z >> SH], 1);
            atomicAdd(&lh[(unsigned)c.w >> SH], 1);
        }
        for (int i = (n4 << 2) + t; i < n; i += THR)
            atomicAdd(&lh[(unsigned)key[s + i] >> SH], 1);
    }
    __syncthreads();
    for (int k = t; k < nb; k += THR) hist[(size_t)b * nb + k] = lh[k];
}

__global__ __launch_bounds__(NBLK) void scan_blocks_kernel(
    int* __restrict__ hist, int* __restrict__ keyTotal, int nb)
{
    __shared__ int sd[NBLK];
    const int t = threadIdx.x, k = blockIdx.x;
    const int v = hist[(size_t)t * nb + k];
    sd[t] = v; __syncthreads();
#pragma unroll
    for (int off = 1; off < NBLK; off <<= 1) {
        int a = (t >= off) ? sd[t - off] : 0;
        __syncthreads();
        sd[t] += a;
        __syncthreads();
    }
    hist[(size_t)t * nb + k] = sd[t] - v;
    if (t == NBLK - 1) keyTotal[k] = sd[t];
}

__global__ __launch_bounds__(1024) void scan_keys_kernel(
    const int* __restrict__ keyTotal, int* __restrict__ keyStart, int nb)
{
    __shared__ int sd[1024];
    const int t = threadIdx.x;
    const int v = (t < nb) ? keyTotal[t] : 0;
    sd[t] = v; __syncthreads();
#pragma unroll
    for (int off = 1; off < 1024; off <<= 1) {
        int a = (t >= off) ? sd[t - off] : 0;
        __syncthreads();
        sd[t] += a;
        __syncthreads();
    }
    if (t < nb) keyStart[t] = sd[t] - v;
    if (t == 0) keyStart[nb] = sd[1023];
}

__global__ __launch_bounds__(THR) void scatter_kernel(
    const int* __restrict__ key, const int* __restrict__ other,
    const int* __restrict__ hist, const int* __restrict__ keyStart,
    unsigned* __restrict__ packed, int nb, int chunk, int n_edges)
{
    __shared__ int lc[MAXNB];
    const int t = threadIdx.x, b = blockIdx.x;
    for (int k = t; k < nb; k += THR)
        lc[k] = keyStart[k] + hist[(size_t)b * nb + k];
    __syncthreads();

    long long s = (long long)b * chunk;
    long long e = s + chunk; if (e > n_edges) e = n_edges;
    if (s < e) {
        const int n = (int)(e - s);
        const int n4 = n >> 2;
        const int4* __restrict__ k4p = reinterpret_cast<const int4*>(key + s);
        const int4* __restrict__ o4p = reinterpret_cast<const int4*>(other + s);
        for (int i = t; i < n4; i += THR) {
            int4 c = k4p[i];
            int4 r = o4p[i];
            int p;
            p = atomicAdd(&lc[(unsigned)c.x >> SH], 1);
            packed[p] = ((unsigned)r.x << SH) | ((unsigned)c.x & (TILE - 1));
            p = atomicAdd(&lc[(unsigned)c.y >> SH], 1);
            packed[p] = ((unsigned)r.y << SH) | ((unsigned)c.y & (TILE - 1));
            p = atomicAdd(&lc[(unsigned)c.z >> SH], 1);
            packed[p] = ((unsigned)r.z << SH) | ((unsigned)c.z & (TILE - 1));
            p = atomicAdd(&lc[(unsigned)c.w >> SH], 1);
            packed[p] = ((unsigned)r.w << SH) | ((unsigned)c.w & (TILE - 1));
        }
        for (int i = (n4 << 2) + t; i < n; i += THR) {
            int c = key[s + i], r = other[s + i];
            int p = atomicAdd(&lc[(unsigned)c >> SH], 1);
            packed[p] = ((unsigned)r << SH) | ((unsigned)c & (TILE - 1));
        }
    }
}

// ---------------- x padding ----------------

__global__ __launch_bounds__(256) void pad_x_kernel(
    const float* __restrict__ x, float4* __restrict__ x4, int n)
{
    const int stride = gridDim.x * 256;
    for (int i = blockIdx.x * 256 + threadIdx.x; i < n; i += stride) {
        float4 v;
        v.x = x[3 * i + 0];
        v.y = x[3 * i + 1];
        v.z = x[3 * i + 2];
        v.w = 0.0f;
        x4[i] = v;
    }
}

// ------- per-bucket row reorder (256-bin counting sort) + window offsets ----

__global__ __launch_bounds__(THR) void reorder_kernel(
    const unsigned* __restrict__ packed, unsigned* __restrict__ packed2,
    const int* __restrict__ keyStart, int* __restrict__ subStart)
{
    __shared__ int h[256];
    __shared__ int sd[256];
    __shared__ int cur[256];
    const int t = threadIdx.x, cb = blockIdx.x;
    if (t < 256) h[t] = 0;
    __syncthreads();

    const int s = keyStart[cb], e = keyStart[cb + 1];

    // pass 1: 256-bin histogram of row>>12 (= p>>24)
    for (int i = s + t; i < e; i += THR)
        atomicAdd(&h[packed[i] >> 24], 1);
    __syncthreads();

    // inclusive scan of h in LDS
    if (t < 256) sd[t] = h[t];
    __syncthreads();
#pragma unroll
    for (int off = 1; off < 256; off <<= 1) {
        int a = 0;
        if (t < 256 && t >= off) a = sd[t - off];
        __syncthreads();
        if (t < 256) sd[t] += a;
        __syncthreads();
    }
    if (t < 256) cur[t] = s + sd[t] - h[t];   // exclusive + segment base
    __syncthreads();

    // window offsets: window w covers bins [w*32, (w+1)*32)
    if (t < NWIN) subStart[cb * (NWIN + 1) + t] = cur[t * 32];
    if (t == 0)   subStart[cb * (NWIN + 1) + NWIN] = e;
    __syncthreads();

    // pass 2: scatter into row-sorted order
    for (int i = s + t; i < e; i += THR) {
        unsigned p = packed[i];
        int q = atomicAdd(&cur[p >> 24], 1);
        packed2[q] = p;
    }
}

// ---------------- window-split agg ----------------

__global__ __launch_bounds__(THR) void agg_win_kernel(
    const unsigned* __restrict__ packed2, const float4* __restrict__ x4,
    const int* __restrict__ subStart, float* __restrict__ partial,
    int n_nodes, int nb)
{
    __shared__ float acc[TILE * 3];   // 48 KB
    const int t = threadIdx.x;
    const int cb = blockIdx.x % nb;       // bucket
    const int w  = blockIdx.x / nb;       // row window (w-major dispatch)
    for (int f = t; f < TILE * 3; f += THR) acc[f] = 0.0f;
    __syncthreads();

    const int s = subStart[cb * (NWIN + 1) + w];
    const int e = subStart[cb * (NWIN + 1) + w + 1];

    int i = s + t;
    for (; i + 3 * THR < e; i += 4 * THR) {
        unsigned p0 = packed2[i];
        unsigned p1 = packed2[i + THR];
        unsigned p2 = packed2[i + 2 * THR];
        unsigned p3 = packed2[i + 3 * THR];
        float4 v0 = x4[p0 >> SH];
        float4 v1 = x4[p1 >> SH];
        float4 v2 = x4[p2 >> SH];
        float4 v3 = x4[p3 >> SH];
        int j0 = (int)(p0 & (TILE - 1)) * 3;
        int j1 = (int)(p1 & (TILE - 1)) * 3;
        int j2 = (int)(p2 & (TILE - 1)) * 3;
        int j3 = (int)(p3 & (TILE - 1)) * 3;
        atomicAdd(&acc[j0 + 0], v0.x); atomicAdd(&acc[j0 + 1], v0.y); atomicAdd(&acc[j0 + 2], v0.z);
        atomicAdd(&acc[j1 + 0], v1.x); atomicAdd(&acc[j1 + 1], v1.y); atomicAdd(&acc[j1 + 2], v1.z);
        atomicAdd(&acc[j2 + 0], v2.x); atomicAdd(&acc[j2 + 1], v2.y); atomicAdd(&acc[j2 + 2], v2.z);
        atomicAdd(&acc[j3 + 0], v3.x); atomicAdd(&acc[j3 + 1], v3.y); atomicAdd(&acc[j3 + 2], v3.z);
    }
    for (; i < e; i += THR) {
        unsigned p = packed2[i];
        float4 v = x4[p >> SH];
        int j = (int)(p & (TILE - 1)) * 3;
        atomicAdd(&acc[j + 0], v.x);
        atomicAdd(&acc[j + 1], v.y);
        atomicAdd(&acc[j + 2], v.z);
    }
    __syncthreads();

    const long long base = (long long)cb << SH;
    long long lim = (long long)n_nodes - base;
    if (lim > TILE) lim = TILE;
    if (lim <= 0) return;
    float* __restrict__ dst = partial + ((size_t)w * n_nodes + base) * 3;
    const int fl = (int)lim * 3;
    for (int f = t; f < fl; f += THR) dst[f] = acc[f];
}

// ---------------- merge NWIN partials + fused MLP ----------------

__global__ __launch_bounds__(256) void merge_mlp_kernel(
    const float* __restrict__ partial, const float* __restrict__ x,
    const float* __restrict__ W1, const float* __restrict__ b1,
    const float* __restrict__ W2, const float* __restrict__ b2,
    const float* __restrict__ W3, const float* __restrict__ b3,
    float* __restrict__ out, int n_nodes)
{
    __shared__ float sW1[96], sb1[16], sW2[256], sb2[16], sW3[48], sb3[3];
    const int t = threadIdx.x;
    if (t < 96)  sW1[t] = W1[t];
    if (t < 16)  sb1[t] = b1[t];
    sW2[t] = W2[t];
    if (t < 16)  sb2[t] = b2[t];
    if (t < 48)  sW3[t] = W3[t];
    if (t < 3)   sb3[t] = b3[t];
    __syncthreads();

    const int i = blockIdx.x * 256 + t;
    if (i >= n_nodes) return;

    float a0 = 0.0f, a1 = 0.0f, a2 = 0.0f;
#pragma unroll
    for (int w = 0; w < NWIN; ++w) {
        const float* __restrict__ p = partial + ((size_t)w * n_nodes + i) * 3;
        a0 += p[0]; a1 += p[1]; a2 += p[2];
    }

    float in6[6];
    in6[0] = x[3 * i + 0];
    in6[1] = x[3 * i + 1];
    in6[2] = x[3 * i + 2];
    in6[3] = a0;
    in6[4] = a1;
    in6[5] = a2;

    float h1[16];
#pragma unroll
    for (int j = 0; j < 16; ++j) {
        float s = sb1[j];
#pragma unroll
        for (int k = 0; k < 6; ++k) s = fmaf(in6[k], sW1[k * 16 + j], s);
        h1[j] = fmaxf(s, 0.0f);
    }
    float h2[16];
#pragma unroll
    for (int j = 0; j < 16; ++j) {
        float s = sb2[j];
#pragma unroll
        for (int k = 0; k < 16; ++k) s = fmaf(h1[k], sW2[k * 16 + j], s);
        h2[j] = fmaxf(s, 0.0f);
    }
    float o0 = sb3[0], o1 = sb3[1], o2 = sb3[2];
#pragma unroll
    for (int j = 0; j < 16; ++j) {
        o0 = fmaf(h2[j], sW3[j * 3 + 0], o0);
        o1 = fmaf(h2[j], sW3[j * 3 + 1], o1);
        o2 = fmaf(h2[j], sW3[j * 3 + 2], o2);
    }
    out[3 * i + 0] = o0;
    out[3 * i + 1] = o1;
    out[3 * i + 2] = o2;
}

// ---------------- Path B: direct gather agg + fused MLP ----------------

__global__ __launch_bounds__(THR) void bucket_agg_mlp_kernel(
    const unsigned* __restrict__ packed, const float* __restrict__ x,
    const int* __restrict__ keyStart,
    const float* __restrict__ W1, const float* __restrict__ b1,
    const float* __restrict__ W2, const float* __restrict__ b2,
    const float* __restrict__ W3, const float* __restrict__ b3,
    float* __restrict__ out, int n_nodes)
{
    __shared__ float acc[TILE * 3];
    __shared__ float sW1[96], sb1[16], sW2[256], sb2[16], sW3[48], sb3[3];
    const int t = threadIdx.x, k = blockIdx.x;

    if (t < 96)  sW1[t] = W1[t];
    if (t < 16)  sb1[t] = b1[t];
    if (t < 256) sW2[t] = W2[t];
    if (t >= 256 && t < 272) sb2[t - 256] = b2[t - 256];
    if (t >= 272 && t < 320) sW3[t - 272] = W3[t - 272];
    if (t >= 320 && t < 323) sb3[t - 320] = b3[t - 320];
    for (int f = t; f < TILE * 3; f += THR) acc[f] = 0.0f;
    __syncthreads();

    const int s = keyStart[k];
    const int e = keyStart[k + 1];
    for (int i = s + t; i < e; i += THR) {
        const unsigned p = packed[i];
        const float* __restrict__ xs = x + 3ll * (p >> SH);
        const int j = (int)(p & (TILE - 1)) * 3;
        atomicAdd(&acc[j + 0], xs[0]);
        atomicAdd(&acc[j + 1], xs[1]);
        atomicAdd(&acc[j + 2], xs[2]);
    }
    __syncthreads();

    const long long base = (long long)k << SH;
    long long lim = (long long)n_nodes - base;
    if (lim > TILE) lim = TILE;
    if (lim <= 0) return;

    for (int j = t; j < (int)lim; j += THR) {
        const long long node = base + j;
        float in6[6];
        in6[0] = x[3 * node + 0];
        in6[1] = x[3 * node + 1];
        in6[2] = x[3 * node + 2];
        in6[3] = acc[3 * j + 0];
        in6[4] = acc[3 * j + 1];
        in6[5] = acc[3 * j + 2];

        float h1[16];
#pragma unroll
        for (int q = 0; q < 16; ++q) {
            float sv = sb1[q];
#pragma unroll
            for (int r = 0; r < 6; ++r) sv = fmaf(in6[r], sW1[r * 16 + q], sv);
            h1[q] = fmaxf(sv, 0.0f);
        }
        float h2[16];
#pragma unroll
        for (int q = 0; q < 16; ++q) {
            float sv = sb2[q];
#pragma unroll
            for (int r = 0; r < 16; ++r) sv = fmaf(h1[r], sW2[r * 16 + q], sv);
            h2[q] = fmaxf(sv, 0.0f);
        }
        float o0 = sb3[0], o1 = sb3[1], o2 = sb3[2];
#pragma unroll
        for (int q = 0; q < 16; ++q) {
            o0 = fmaf(h2[q], sW3[q * 3 + 0], o0);
            o1 = fmaf(h2[q], sW3[q * 3 + 1], o1);
            o2 = fmaf(h2[q], sW3[q * 3 + 2], o2);
        }
        out[3 * node + 0] = o0;
        out[3 * node + 1] = o1;
        out[3 * node + 2] = o2;
    }
}

// ---------------- Path C ----------------

__global__ __launch_bounds__(256) void edge_scatter_kernel(
    const int* __restrict__ rows, const int* __restrict__ cols,
    const float* __restrict__ x, float* __restrict__ agg, int n_edges)
{
    const long long tid = (long long)blockIdx.x * blockDim.x + threadIdx.x;
    const long long stride = (long long)gridDim.x * blockDim.x;
    for (long long i = tid; i < n_edges; i += stride) {
        int r = rows[i], c = cols[i];
        const float* xs = x + 3ll * r; float* a = agg + 3ll * c;
        atomicAdd(a + 0, xs[0]); atomicAdd(a + 1, xs[1]); atomicAdd(a + 2, xs[2]);
    }
}

__global__ __launch_bounds__(256) void node_mlp_kernel(
    const float* __restrict__ x,
    const float* __restrict__ W1, const float* __restrict__ b1,
    const float* __restrict__ W2, const float* __restrict__ b2,
    const float* __restrict__ W3, const float* __restrict__ b3,
    float* __restrict__ out, int n_nodes)
{
    __shared__ float sW1[96], sb1[16], sW2[256], sb2[16], sW3[48], sb3[3];
    const int t = threadIdx.x;
    if (t < 96)  sW1[t] = W1[t];
    if (t < 16)  sb1[t] = b1[t];
    sW2[t] = W2[t];
    if (t < 16)  sb2[t] = b2[t];
    if (t < 48)  sW3[t] = W3[t];
    if (t < 3)   sb3[t] = b3[t];
    __syncthreads();

    const int i = blockIdx.x * 256 + t;
    if (i >= n_nodes) return;

    float in6[6];
    in6[0] = x[3 * i + 0];
    in6[1] = x[3 * i + 1];
    in6[2] = x[3 * i + 2];
    in6[3] = out[3 * i + 0];
    in6[4] = out[3 * i + 1];
    in6[5] = out[3 * i + 2];

    float h1[16];
#pragma unroll
    for (int j = 0; j < 16; ++j) {
        float s = sb1[j];
#pragma unroll
        for (int k = 0; k < 6; ++k) s = fmaf(in6[k], sW1[k * 16 + j], s);
        h1[j] = fmaxf(s, 0.0f);
    }
    float h2[16];
#pragma unroll
    for (int j = 0; j < 16; ++j) {
        float s = sb2[j];
#pragma unroll
        for (int k = 0; k < 16; ++k) s = fmaf(h1[k], sW2[k * 16 + j], s);
        h2[j] = fmaxf(s, 0.0f);
    }
    float o[3];
#pragma unroll
    for (int c = 0; c < 3; ++c) {
        float s = sb3[c];
#pragma unroll
        for (int j = 0; j < 16; ++j) s = fmaf(h2[j], sW3[j * 3 + c], s);
        o[c] = s;
    }
    out[3 * i + 0] = o[0];
    out[3 * i + 1] = o[1];
    out[3 * i + 2] = o[2];
}

extern "C" void kernel_launch(void* const* d_in, const int* in_sizes, int n_in,
                              void* d_out, int out_size, void* d_ws, size_t ws_size,
                              hipStream_t stream) {
    const float* x   = (const float*)d_in[0];
    const int*   ei  = (const int*)d_in[1];   // [2, E] int32
    const float* W1  = (const float*)d_in[5];
    const float* b1  = (const float*)d_in[6];
    const float* W2  = (const float*)d_in[7];
    const float* b2  = (const float*)d_in[8];
    const float* W3  = (const float*)d_in[9];
    const float* b3  = (const float*)d_in[10];

    const int n_nodes = in_sizes[0] / 3;
    const int n_edges = in_sizes[1] / 2;
    const int* rows = ei;            // edge_index[0]
    const int* cols = ei + n_edges;  // edge_index[1]
    float* out = (float*)d_out;

    const int nb = (n_nodes + TILE - 1) >> SH;

    int chunk = (n_edges + NBLK - 1) / NBLK;
    chunk = (chunk + 3) & ~3;        // keep per-block int4 loads 16B-aligned

    // Path A layout: x4[N] f4 | packed[E] | packed2[E] | partial[NWIN*N*3]
    //                | hist[NBLK*nb] | keyTotal[nb] | keyStart[nb+1]
    //                | subStart[nb*(NWIN+1)]
    const size_t off_x4     = 0;
    const size_t off_packed = off_x4 + (size_t)n_nodes * 16;
    const size_t off_pk2    = off_packed + (size_t)n_edges * 4;
    const size_t off_part   = off_pk2 + (size_t)n_edges * 4;
    const size_t off_hist   = off_part + (size_t)NWIN * n_nodes * 12;
    const size_t off_kt     = off_hist + (size_t)NBLK * nb * 4;
    const size_t off_ks     = off_kt + (size_t)nb * 4;
    const size_t off_ss     = off_ks + (size_t)(nb + 1) * 4;
    const size_t needA      = off_ss + (size_t)nb * (NWIN + 1) * 4;

    const size_t needB = (size_t)n_edges * 4 + (size_t)NBLK * nb * 4
                       + (size_t)nb * 4 + (size_t)(nb + 1) * 4;
    const bool okA = (ws_size >= needA) && (nb <= MAXNB) && (n_nodes <= (1 << 20));
    const bool okB = (ws_size >= needB) && (nb <= MAXNB) && (n_nodes <= (1 << 20));

    if (okA) {
        float4*   x4       = (float4*)((char*)d_ws + off_x4);
        unsigned* packed   = (unsigned*)((char*)d_ws + off_packed);
        unsigned* packed2  = (unsigned*)((char*)d_ws + off_pk2);
        float*    partial  = (float*)((char*)d_ws + off_part);
        int*      hist     = (int*)((char*)d_ws + off_hist);
        int*      keyTotal = (int*)((char*)d_ws + off_kt);
        int*      keyStart = (int*)((char*)d_ws + off_ks);
        int*      subStart = (int*)((char*)d_ws + off_ss);

        pad_x_kernel<<<2048, 256, 0, stream>>>(x, x4, n_nodes);
        hist_kernel<<<NBLK, THR, 0, stream>>>(cols, hist, nb, chunk, n_edges);
        scan_blocks_kernel<<<nb, NBLK, 0, stream>>>(hist, keyTotal, nb);
        scan_keys_kernel<<<1, 1024, 0, stream>>>(keyTotal, keyStart, nb);
        scatter_kernel<<<NBLK, THR, 0, stream>>>(cols, rows, hist, keyStart,
                                                 packed, nb, chunk, n_edges);
        reorder_kernel<<<nb, THR, 0, stream>>>(packed, packed2, keyStart, subStart);
        agg_win_kernel<<<nb * NWIN, THR, 0, stream>>>(packed2, x4, subStart,
                                                      partial, n_nodes, nb);
        merge_mlp_kernel<<<(n_nodes + 255) / 256, 256, 0, stream>>>(
            partial, x, W1, b1, W2, b2, W3, b3, out, n_nodes);
    } else if (okB) {
        unsigned* packed = (unsigned*)d_ws;
        int* hist        = (int*)(packed + n_edges);
        int* keyTotal    = hist + (size_t)NBLK * nb;
        int* keyStart    = keyTotal + nb;

        hist_kernel<<<NBLK, THR, 0, stream>>>(cols, hist, nb, chunk, n_edges);
        scan_blocks_kernel<<<nb, NBLK, 0, stream>>>(hist, keyTotal, nb);
        scan_keys_kernel<<<1, 1024, 0, stream>>>(keyTotal, keyStart, nb);
        scatter_kernel<<<NBLK, THR, 0, stream>>>(cols, rows, hist, keyStart,
                                                 packed, nb, chunk, n_edges);
        bucket_agg_mlp_kernel<<<nb, THR, 0, stream>>>(
            packed, x, keyStart, W1, b1, W2, b2, W3, b3, out, n_nodes);
    } else {
        hipMemsetAsync(d_out, 0, (size_t)out_size * sizeof(float), stream);
        edge_scatter_kernel<<<8192, 256, 0, stream>>>(rows, cols, x, out, n_edges);
        node_mlp_kernel<<<(n_nodes + 255) / 256, 256, 0, stream>>>(
            x, W1, b1, W2, b2, W3, b3, out, n_nodes);
    }
}